// Round 1
// baseline (1355.329 us; speedup 1.0000x reference)
//
#include <hip/hip_runtime.h>

#define RNN_B 64
#define RNN_T 1024
#define RNN_D 256
#define RNN_H 256

// ---------------------------------------------------------------------------
// Kernel 1: xp[b,t,:] = x[b,t,:] @ Wx + b   (written into the hs region of out)
// Each block: 8 rows of (b*t), 256 threads (thread j = output column).
// x rows staged in LDS (broadcast reads), Wx streamed from L2 (coalesced).
// ---------------------------------------------------------------------------
__global__ __launch_bounds__(256) void xp_gemm_kernel(
    const float* __restrict__ x, const float* __restrict__ Wx,
    const float* __restrict__ bias, float* __restrict__ xp) {
  __shared__ float xs[8][RNN_D];
  const int j = threadIdx.x;                  // output column 0..255
  const size_t row0 = (size_t)blockIdx.x * 8; // first (b*t) row

  // cooperative stage of 8 x-rows (8*256 f32 = 512 float4, 2 per thread)
  const float4* xg = reinterpret_cast<const float4*>(x + row0 * RNN_D);
  float4* xsv = reinterpret_cast<float4*>(&xs[0][0]);
  xsv[j] = xg[j];
  xsv[j + 256] = xg[j + 256];
  __syncthreads();

  const float bj = bias[j];
  float acc[8];
#pragma unroll
  for (int r = 0; r < 8; ++r) acc[r] = bj;

  for (int k = 0; k < RNN_D; k += 4) {
    const float w0 = Wx[(size_t)(k + 0) * RNN_H + j];
    const float w1 = Wx[(size_t)(k + 1) * RNN_H + j];
    const float w2 = Wx[(size_t)(k + 2) * RNN_H + j];
    const float w3 = Wx[(size_t)(k + 3) * RNN_H + j];
#pragma unroll
    for (int r = 0; r < 8; ++r) {
      const float4 xv = *reinterpret_cast<const float4*>(&xs[r][k]);
      acc[r] = fmaf(xv.x, w0, acc[r]);
      acc[r] = fmaf(xv.y, w1, acc[r]);
      acc[r] = fmaf(xv.z, w2, acc[r]);
      acc[r] = fmaf(xv.w, w3, acc[r]);
    }
  }
#pragma unroll
  for (int r = 0; r < 8; ++r) xp[(row0 + r) * RNN_H + j] = acc[r];
}

// ---------------------------------------------------------------------------
// Kernel 2: sequential scan. One workgroup per batch element b.
// 1024 threads: thread (j0 = tid>>3, c = tid&7) computes partial dots for
// output columns j0 and j0+128 over k in [32c, 32c+32). Wh slice (64 f32)
// lives in registers. h double-buffered in LDS, padded 36 floats per 32-chunk
// so the 8 distinct broadcast addresses per wave hit disjoint bank quads.
// 8-lane shfl_xor reduction; lane c==0 finalizes (tanh) and writes.
// xp is read in place from `out` and overwritten with h_t (same thread owns
// read+write of each address -> no race). xp[t+1] prefetched during step t.
// ---------------------------------------------------------------------------
__global__ __launch_bounds__(1024, 4) void rnn_rec_kernel(
    const float* __restrict__ Wh, const float* __restrict__ h0,
    float* __restrict__ out, float* __restrict__ h_last) {
  const int b = blockIdx.x;
  const int tid = threadIdx.x;
  const int c = tid & 7;      // k-chunk 0..7 (32 k each)
  const int j0 = tid >> 3;    // 0..127 ; handles columns j0 and j0+128
  const int j1 = j0 + 128;

  __shared__ float hbuf[2][8 * 36];  // h[g] stored at [(g>>5)*36 + (g&31)]

  // one-time Wh slice load into registers
  float wh0[32], wh1[32];
  {
    const float* wr = Wh + (size_t)(32 * c) * RNN_H;
#pragma unroll
    for (int i = 0; i < 32; ++i) {
      wh0[i] = wr[(size_t)i * RNN_H + j0];
      wh1[i] = wr[(size_t)i * RNN_H + j1];
    }
  }

  if (tid < RNN_H) {
    hbuf[0][(tid >> 5) * 36 + (tid & 31)] = h0[b * RNN_H + tid];
  }
  __syncthreads();

  float* outb = out + (size_t)b * RNN_T * RNN_H;
  float xc0 = 0.f, xc1 = 0.f;
  if (c == 0) { xc0 = outb[j0]; xc1 = outb[j1]; }

  int p = 0;
  for (int t = 0; t < RNN_T; ++t) {
    // prefetch next step's xp (hidden under the FMA loop)
    float xn0 = 0.f, xn1 = 0.f;
    if (c == 0 && t + 1 < RNN_T) {
      xn0 = outb[(size_t)(t + 1) * RNN_H + j0];
      xn1 = outb[(size_t)(t + 1) * RNN_H + j1];
    }

    const float* hb = &hbuf[p][c * 36];
    float s0 = 0.f, s1 = 0.f;
#pragma unroll
    for (int i = 0; i < 32; i += 4) {
      const float4 hv = *reinterpret_cast<const float4*>(&hb[i]);
      s0 = fmaf(hv.x, wh0[i + 0], s0); s1 = fmaf(hv.x, wh1[i + 0], s1);
      s0 = fmaf(hv.y, wh0[i + 1], s0); s1 = fmaf(hv.y, wh1[i + 1], s1);
      s0 = fmaf(hv.z, wh0[i + 2], s0); s1 = fmaf(hv.z, wh1[i + 2], s1);
      s0 = fmaf(hv.w, wh0[i + 3], s0); s1 = fmaf(hv.w, wh1[i + 3], s1);
    }
    // reduce across the 8 c-lanes (lanes tid..tid^7 within the wave)
    s0 += __shfl_xor(s0, 1); s1 += __shfl_xor(s1, 1);
    s0 += __shfl_xor(s0, 2); s1 += __shfl_xor(s1, 2);
    s0 += __shfl_xor(s0, 4); s1 += __shfl_xor(s1, 4);

    if (c == 0) {
      const float h0n = tanhf(xc0 + s0);
      const float h1n = tanhf(xc1 + s1);
      hbuf[p ^ 1][(j0 >> 5) * 36 + (j0 & 31)] = h0n;
      hbuf[p ^ 1][(j1 >> 5) * 36 + (j1 & 31)] = h1n;
      outb[(size_t)t * RNN_H + j0] = h0n;
      outb[(size_t)t * RNN_H + j1] = h1n;
      if (t == RNN_T - 1) {
        h_last[b * RNN_H + j0] = h0n;
        h_last[b * RNN_H + j1] = h1n;
      }
    }
    __syncthreads();
    p ^= 1;
    xc0 = xn0; xc1 = xn1;
  }
}

extern "C" void kernel_launch(void* const* d_in, const int* in_sizes, int n_in,
                              void* d_out, int out_size, void* d_ws, size_t ws_size,
                              hipStream_t stream) {
  const float* x    = (const float*)d_in[0];
  const float* h0   = (const float*)d_in[1];
  const float* Wx   = (const float*)d_in[2];
  const float* Wh   = (const float*)d_in[3];
  const float* bias = (const float*)d_in[4];
  float* out = (float*)d_out;
  float* h_last = out + (size_t)RNN_B * RNN_T * RNN_H;

  // Stage 1: xp -> hs region of out (in-place consumed by stage 2)
  xp_gemm_kernel<<<RNN_B * RNN_T / 8, 256, 0, stream>>>(x, Wx, bias, out);
  // Stage 2: sequential recurrence, one WG per batch row
  rnn_rec_kernel<<<RNN_B, 1024, 0, stream>>>(Wh, h0, out, h_last);
}